// Round 7
// baseline (95.376 us; speedup 1.0000x reference)
//
#include <hip/hip_runtime.h>

#define B_   4
#define LQ_  256
#define LK_  512
#define DIN_ 512
#define H_   256
#define DV_  512

// 2*log2(e): folded into projections so tanh(x) = 1 - 2*rcp(exp2(x')+1), x'=2x*log2e
#define TANH_SCALE 2.885390081777927f

// =====================================================================
// Kernel A: projections. 16 rows/block (W reuse), X staged in LDS (32 KB).
// 256 thr: hq=t&63 -> h=4*hq (float4 W loads, full 1KB/wave coalesced),
//          rg=t>>6 -> rows rg*4..rg*4+3.  16 acc chains/thread.
// Per d-group (d+=8): 8 independent float4 W loads vs 256 cyc of FMA.
//  q blocks -> qT[b][h][i] (transposed, scaled; float4 along i)
//  k blocks -> kp[b][j][h] (row-major, scaled; float4 along h)
// grid = 1024/16 + 2048/16 = 64 + 128 = 192 blocks.
// =====================================================================
__global__ __launch_bounds__(256) void proj_kernel(
    const float* __restrict__ Q, const float* __restrict__ K,
    const float* __restrict__ Wq, const float* __restrict__ Wk,
    const float* __restrict__ wv, const int* __restrict__ valid_lens,
    float* __restrict__ qT, float* __restrict__ kp, float* __restrict__ wsum) {
  __shared__ float xs[16][DIN_];   // 32 KB
  const int blk = blockIdx.x;
  const bool isQ = blk < (B_ * LQ_ / 16);
  const int flat = (isQ ? blk : blk - B_ * LQ_ / 16) * 16;
  const int b    = isQ ? (flat >> 8) : (flat >> 9);
  const int rloc = isQ ? (flat & (LQ_ - 1)) : (flat & (LK_ - 1));
  if (!isQ && rloc >= valid_lens[b]) return;   // masked K tile: never read later

  const float* __restrict__ X = (isQ ? Q : K) + (size_t)flat * DIN_;
  const float* __restrict__ W = isQ ? Wq : Wk;
  const int t = threadIdx.x;

  // stage 16 rows x 512 d: 2048 float4 / 256 thr = 8 each, coalesced
#pragma unroll
  for (int u = 0; u < 8; ++u) {
    const int f = t + 256 * u;               // float4 idx 0..2047
    const int r = f >> 7, c4 = (f & 127) << 2;
    *(float4*)&xs[r][c4] = *(const float4*)&X[(size_t)r * DIN_ + c4];
  }
  __syncthreads();

  const int hq = t & 63;     // h quad: h = 4*hq
  const int rg = t >> 6;     // row group: rows rg*4 .. rg*4+3
  float acc[4][4];           // [row][h-sub]
#pragma unroll
  for (int r = 0; r < 4; ++r)
#pragma unroll
    for (int c = 0; c < 4; ++c) acc[r][c] = 0.f;

  for (int d = 0; d < DIN_; d += 8) {
    float4 w[8];
#pragma unroll
    for (int u = 0; u < 8; ++u)                         // 8 x 1KB loads in flight
      w[u] = *(const float4*)&W[(size_t)(d + u) * H_ + 4 * hq];
#pragma unroll
    for (int r = 0; r < 4; ++r) {
      const int row = rg * 4 + r;
      const float4 xa = *(const float4*)&xs[row][d];
      const float4 xb = *(const float4*)&xs[row][d + 4];
      const float xv[8] = {xa.x, xa.y, xa.z, xa.w, xb.x, xb.y, xb.z, xb.w};
#pragma unroll
      for (int u = 0; u < 8; ++u) {
        acc[r][0] = fmaf(xv[u], w[u].x, acc[r][0]);
        acc[r][1] = fmaf(xv[u], w[u].y, acc[r][1]);
        acc[r][2] = fmaf(xv[u], w[u].z, acc[r][2]);
        acc[r][3] = fmaf(xv[u], w[u].w, acc[r][3]);
      }
    }
  }

  if (isQ) {
    // qT[b][h][i]: for each of 4 h's, the 4 rows are consecutive i -> float4
#pragma unroll
    for (int c = 0; c < 4; ++c) {
      float4 o = {acc[0][c] * TANH_SCALE, acc[1][c] * TANH_SCALE,
                  acc[2][c] * TANH_SCALE, acc[3][c] * TANH_SCALE};
      *(float4*)&qT[((size_t)b * H_ + 4 * hq + c) * LQ_ + rloc + rg * 4] = o;
    }
  } else {
    // kp[b][j][h]: float4 along h per row
#pragma unroll
    for (int r = 0; r < 4; ++r) {
      float4 o = {acc[r][0] * TANH_SCALE, acc[r][1] * TANH_SCALE,
                  acc[r][2] * TANH_SCALE, acc[r][3] * TANH_SCALE};
      *(float4*)&kp[(size_t)(flat + rg * 4 + r) * H_ + 4 * hq] = o;
    }
  }

  if (blk == 0 && t < 64) {
    float s = wv[t] + wv[t + 64] + wv[t + 128] + wv[t + 192];
#pragma unroll
    for (int off = 32; off; off >>= 1) s += __shfl_xor(s, off);
    if (t == 0) *wsum = s;
  }
}

// =====================================================================
// Kernel B: scoresT[b,j,i] = Wsum - 2*sum_h wv[h]*rcp(1+exp2(qT+kp))
// 1024 thr = 256 i (lane) x 4 j (wave-uniform). grid = B*LK/4 = 512 blocks,
// ~half live after masking -> ~18 waves/CU. q coalesced, k/wv scalar.
// =====================================================================
__global__ __launch_bounds__(1024) void scores_kernel(
    const float* __restrict__ qT, const float* __restrict__ kp,
    const float* __restrict__ wv, const float* __restrict__ wsum,
    const int* __restrict__ valid_lens, float* __restrict__ scT) {
  const int blk = blockIdx.x;
  const int b  = blk >> 7;
  const int j0 = (blk & 127) * 4;
  const int vl = valid_lens[b];
  if (j0 >= vl) return;                      // whole block masked
  const int t = threadIdx.x;
  const int i  = t & 255;
  const int jj = t >> 8;                     // wave-uniform
  const int j = j0 + jj;
  if (j >= vl) return;                       // wave-uniform skip

  const float* __restrict__ qcol = qT + (size_t)b * H_ * LQ_ + i;
  const float* __restrict__ krow = kp + (size_t)(b * LK_ + j) * H_;   // uniform
  const float Wsum = *wsum;

  float a = 0.f;
  for (int h = 0; h < H_; h += 8) {
    float qv[8];
#pragma unroll
    for (int u = 0; u < 8; ++u) qv[u] = qcol[(size_t)(h + u) * LQ_];  // 8 in flight
    const float4 ka = *(const float4*)&krow[h];
    const float4 kb = *(const float4*)&krow[h + 4];
    const float4 wa = *(const float4*)&wv[h];
    const float4 wb = *(const float4*)&wv[h + 4];
    const float kk[8] = {ka.x, ka.y, ka.z, ka.w, kb.x, kb.y, kb.z, kb.w};
    const float ww[8] = {wa.x, wa.y, wa.z, wa.w, wb.x, wb.y, wb.z, wb.w};
#pragma unroll
    for (int u = 0; u < 8; ++u)
      a = fmaf(ww[u], __builtin_amdgcn_rcpf(exp2f(qv[u] + kk[u]) + 1.f), a);
  }
  scT[((size_t)b * LK_ + j) * LQ_ + i] = fmaf(-2.f, a, Wsum);  // coalesced
}

// =====================================================================
// Kernel C: masked softmax + AV, TI=4 rows/block, 512 thr, AV unroll x8.
// =====================================================================
__global__ __launch_bounds__(512) void softmax_av_kernel(
    const float* __restrict__ scT, const float* __restrict__ V,
    const int* __restrict__ valid_lens, float* __restrict__ out) {
  __shared__ float4 p4s[LK_];
  __shared__ float redm[8][4];
  __shared__ float reds[8][4];

  const int blk = blockIdx.x;
  const int b = blk >> 6;
  const int i0 = (blk & 63) * 4;
  const int vl = valid_lens[b];
  const int t = threadIdx.x;        // j
  const int lane = t & 63, wave = t >> 6;

  const bool valid = t < vl;
  float s[4], m[4];
  {
    float4 sv = {-3.0e38f, -3.0e38f, -3.0e38f, -3.0e38f};
    if (valid) sv = *(const float4*)&scT[((size_t)b * LK_ + t) * LQ_ + i0];
    s[0] = sv.x; s[1] = sv.y; s[2] = sv.z; s[3] = sv.w;
#pragma unroll
    for (int ii = 0; ii < 4; ++ii) m[ii] = s[ii];
  }
#pragma unroll
  for (int off = 32; off; off >>= 1)
#pragma unroll
    for (int ii = 0; ii < 4; ++ii) m[ii] = fmaxf(m[ii], __shfl_xor(m[ii], off));
  if (lane == 0)
#pragma unroll
    for (int ii = 0; ii < 4; ++ii) redm[wave][ii] = m[ii];
  __syncthreads();
  float e[4], sum[4];
#pragma unroll
  for (int ii = 0; ii < 4; ++ii) {
    float mx = redm[0][ii];
#pragma unroll
    for (int w = 1; w < 8; ++w) mx = fmaxf(mx, redm[w][ii]);
    e[ii] = valid ? __expf(s[ii] - mx) : 0.f;
    sum[ii] = e[ii];
  }
#pragma unroll
  for (int off = 32; off; off >>= 1)
#pragma unroll
    for (int ii = 0; ii < 4; ++ii) sum[ii] += __shfl_xor(sum[ii], off);
  if (lane == 0)
#pragma unroll
    for (int ii = 0; ii < 4; ++ii) reds[wave][ii] = sum[ii];
  __syncthreads();
  {
    float4 pv;
    float tot[4];
#pragma unroll
    for (int ii = 0; ii < 4; ++ii) {
      tot[ii] = reds[0][ii];
#pragma unroll
      for (int w = 1; w < 8; ++w) tot[ii] += reds[w][ii];
    }
    pv.x = e[0] * __builtin_amdgcn_rcpf(tot[0]);
    pv.y = e[1] * __builtin_amdgcn_rcpf(tot[1]);
    pv.z = e[2] * __builtin_amdgcn_rcpf(tot[2]);
    pv.w = e[3] * __builtin_amdgcn_rcpf(tot[3]);
    p4s[t] = pv;
  }
  __syncthreads();

  const float* __restrict__ Vb = V + (size_t)b * LK_ * DV_ + t;
  float a[4] = {0.f, 0.f, 0.f, 0.f};
  int j = 0;
  const int jv = vl & ~7;
  for (; j < jv; j += 8) {
    float v[8];
#pragma unroll
    for (int u = 0; u < 8; ++u) v[u] = Vb[(size_t)(j + u) * DV_];
#pragma unroll
    for (int u = 0; u < 8; ++u) {
      const float4 pp = p4s[j + u];
      a[0] = fmaf(pp.x, v[u], a[0]); a[1] = fmaf(pp.y, v[u], a[1]);
      a[2] = fmaf(pp.z, v[u], a[2]); a[3] = fmaf(pp.w, v[u], a[3]);
    }
  }
  for (; j < vl; ++j) {
    const float v = Vb[(size_t)j * DV_];
    const float4 pp = p4s[j];
    a[0] = fmaf(pp.x, v, a[0]); a[1] = fmaf(pp.y, v, a[1]);
    a[2] = fmaf(pp.z, v, a[2]); a[3] = fmaf(pp.w, v, a[3]);
  }
#pragma unroll
  for (int ii = 0; ii < 4; ++ii)
    out[(size_t)(b * LQ_ + i0 + ii) * DV_ + t] = a[ii];
}

extern "C" void kernel_launch(void* const* d_in, const int* in_sizes, int n_in,
                              void* d_out, int out_size, void* d_ws, size_t ws_size,
                              hipStream_t stream) {
  const float* queries    = (const float*)d_in[0];
  const float* keys       = (const float*)d_in[1];
  const float* values     = (const float*)d_in[2];
  const int*   valid_lens = (const int*)d_in[3];
  const float* Wq         = (const float*)d_in[4];
  const float* Wk         = (const float*)d_in[5];
  const float* wv         = (const float*)d_in[6];
  float* out = (float*)d_out;

  char* ws = (char*)d_ws;
  float* qT   = (float*)ws;                          // B*H*LQ  = 1 MB
  float* kp   = (float*)(ws + (size_t)(1 << 20));    // B*LK*H  = 2 MB
  float* scT  = (float*)(ws + (size_t)(3 << 20));    // B*LK*LQ = 2 MB
  float* wsum = (float*)(ws + (size_t)(5 << 20));    // 4 B

  proj_kernel<<<(B_ * LQ_ + B_ * LK_) / 16, 256, 0, stream>>>(
      queries, keys, Wq, Wk, wv, valid_lens, qT, kp, wsum);
  scores_kernel<<<B_ * (LK_ / 4), 1024, 0, stream>>>(
      qT, kp, wv, wsum, valid_lens, scT);
  softmax_av_kernel<<<B_ * (LQ_ / 4), 512, 0, stream>>>(
      scT, values, valid_lens, out);
}

// Round 8
// 72.823 us; speedup vs baseline: 1.3097x; 1.3097x over previous
//
#include <hip/hip_runtime.h>

#define B_   4
#define LQ_  256
#define LK_  512
#define DIN_ 512
#define H_   256
#define DV_  512

// 2*log2(e): folded into projections so tanh(x) = 1 - 2*rcp(exp2(x')+1), x'=2x*log2e
#define TANH_SCALE 2.885390081777927f

// =====================================================================
// Kernel A: projections. 8 rows/block, 512 thr, 4-way d-split.
//   thread = (hq = t&63 -> h=4hq..4hq+3, rg = (t>>6)&1 -> rows rg*4..+3,
//             dh = t>>7 -> d in [dh*128, dh*128+128))
//   acc[4 rows][4 h]; per d-group of 8: 8 independent float4 W loads
//   vs 128 FMA (256 wave-cyc) -> latency hidden at low occupancy.
//   d-parts combined via LDS (stride-17 pad, conflict-free).
//  q blocks -> qT[b][h][i] (transposed, scaled; float4 along i)
//  k blocks -> kp[b][j][h] (row-major, scaled; float4 along h)
// grid = 1024/8 + 2048/8 = 128 + 256 = 384 blocks; masked K blocks exit.
// =====================================================================
__global__ __launch_bounds__(512) void proj_kernel(
    const float* __restrict__ Q, const float* __restrict__ K,
    const float* __restrict__ Wq, const float* __restrict__ Wk,
    const float* __restrict__ wv, const int* __restrict__ valid_lens,
    float* __restrict__ qT, float* __restrict__ kp, float* __restrict__ wsum) {
  __shared__ float xs[8][DIN_];        // 16 KB
  __shared__ float comb[3][128][17];   // 26.6 KB, stride 17 -> conflict-free
  const int blk = blockIdx.x;
  const bool isQ = blk < (B_ * LQ_ / 8);
  const int flat = (isQ ? blk : blk - B_ * LQ_ / 8) * 8;
  const int b    = isQ ? (flat >> 8) : (flat >> 9);
  const int rloc = isQ ? (flat & (LQ_ - 1)) : (flat & (LK_ - 1));
  if (!isQ && rloc >= valid_lens[b]) return;   // uniform exit, before barriers

  const float* __restrict__ X = (isQ ? Q : K) + (size_t)flat * DIN_;
  const float* __restrict__ W = isQ ? Wq : Wk;
  const int t  = threadIdx.x;
  const int hq = t & 63;
  const int rg = (t >> 6) & 1;
  const int dh = t >> 7;               // 0..3

  // stage 8 rows x 512 d: 1024 float4 / 512 thr = 2 each, coalesced
#pragma unroll
  for (int u = 0; u < 2; ++u) {
    const int f = t + 512 * u;
    const int r = f >> 7, c4 = (f & 127) << 2;
    *(float4*)&xs[r][c4] = *(const float4*)&X[(size_t)r * DIN_ + c4];
  }
  __syncthreads();

  float acc[4][4];
#pragma unroll
  for (int r = 0; r < 4; ++r)
#pragma unroll
    for (int c = 0; c < 4; ++c) acc[r][c] = 0.f;

  const int d0 = dh * 128;
  for (int dd = 0; dd < 128; dd += 8) {
    const int d = d0 + dd;
    float4 w4[8];
#pragma unroll
    for (int u = 0; u < 8; ++u)                     // 8 x 1KB/wave loads in flight
      w4[u] = *(const float4*)&W[(size_t)(d + u) * H_ + 4 * hq];
#pragma unroll
    for (int r = 0; r < 4; ++r) {
      const int row = rg * 4 + r;
      const float4 xa = *(const float4*)&xs[row][d];
      const float4 xb = *(const float4*)&xs[row][d + 4];
      const float xv[8] = {xa.x, xa.y, xa.z, xa.w, xb.x, xb.y, xb.z, xb.w};
#pragma unroll
      for (int u = 0; u < 8; ++u) {
        acc[r][0] = fmaf(xv[u], w4[u].x, acc[r][0]);
        acc[r][1] = fmaf(xv[u], w4[u].y, acc[r][1]);
        acc[r][2] = fmaf(xv[u], w4[u].z, acc[r][2]);
        acc[r][3] = fmaf(xv[u], w4[u].w, acc[r][3]);
      }
    }
  }

  // combine the 4 d-parts
  const int lid = t & 127;             // (hq, rg)
  if (dh > 0) {
#pragma unroll
    for (int r = 0; r < 4; ++r)
#pragma unroll
      for (int c = 0; c < 4; ++c) comb[dh - 1][lid][4 * r + c] = acc[r][c];
  }
  __syncthreads();
  if (dh == 0) {
#pragma unroll
    for (int p = 0; p < 3; ++p)
#pragma unroll
      for (int r = 0; r < 4; ++r)
#pragma unroll
        for (int c = 0; c < 4; ++c) acc[r][c] += comb[p][lid][4 * r + c];

    if (isQ) {
      // qT[b][h][i]: 4 rows are consecutive i -> float4 per h
#pragma unroll
      for (int c = 0; c < 4; ++c) {
        float4 o = {acc[0][c] * TANH_SCALE, acc[1][c] * TANH_SCALE,
                    acc[2][c] * TANH_SCALE, acc[3][c] * TANH_SCALE};
        *(float4*)&qT[((size_t)b * H_ + 4 * hq + c) * LQ_ + rloc + rg * 4] = o;
      }
    } else {
      // kp[b][j][h]: float4 along h per row
#pragma unroll
      for (int r = 0; r < 4; ++r) {
        float4 o = {acc[r][0] * TANH_SCALE, acc[r][1] * TANH_SCALE,
                    acc[r][2] * TANH_SCALE, acc[r][3] * TANH_SCALE};
        *(float4*)&kp[(size_t)(flat + rg * 4 + r) * H_ + 4 * hq] = o;
      }
    }
  }

  if (blk == 0 && t < 64) {
    float s = wv[t] + wv[t + 64] + wv[t + 128] + wv[t + 192];
#pragma unroll
    for (int off = 32; off; off >>= 1) s += __shfl_xor(s, off);
    if (t == 0) *wsum = s;
  }
}

// =====================================================================
// Kernel B: scoresT[b,j,i] = Wsum - 2*sum_h wv[h]*rcp(1+exp2(qT+kp))
// j-MAJOR grid: blk = jc*B + b  -> live blocks form a dense prefix,
// spread evenly over CUs. 512 thr = 256 i (lane) x 2 j (wave-uniform).
// grid = (LK/2)*B = 1024 blocks, ~half live -> ~16 waves/CU.
// =====================================================================
__global__ __launch_bounds__(512) void scores_kernel(
    const float* __restrict__ qT, const float* __restrict__ kp,
    const float* __restrict__ wv, const float* __restrict__ wsum,
    const int* __restrict__ valid_lens, float* __restrict__ scT) {
  const int blk = blockIdx.x;
  const int b  = blk & (B_ - 1);
  const int j0 = (blk >> 2) * 2;
  const int vl = valid_lens[b];
  if (j0 >= vl) return;                      // whole block masked
  const int t = threadIdx.x;
  const int i  = t & 255;
  const int jj = t >> 8;                     // wave-uniform (0 or 1)
  const int j = j0 + jj;
  if (j >= vl) return;                       // wave-uniform skip

  const float* __restrict__ qcol = qT + (size_t)b * H_ * LQ_ + i;
  const float* __restrict__ krow = kp + (size_t)(b * LK_ + j) * H_;   // uniform
  const float Wsum = *wsum;

  float a = 0.f;
  for (int h = 0; h < H_; h += 8) {
    float qv[8];
#pragma unroll
    for (int u = 0; u < 8; ++u) qv[u] = qcol[(size_t)(h + u) * LQ_];  // 8 in flight
    const float4 ka = *(const float4*)&krow[h];
    const float4 kb = *(const float4*)&krow[h + 4];
    const float4 wa = *(const float4*)&wv[h];
    const float4 wb = *(const float4*)&wv[h + 4];
    const float kk[8] = {ka.x, ka.y, ka.z, ka.w, kb.x, kb.y, kb.z, kb.w};
    const float ww[8] = {wa.x, wa.y, wa.z, wa.w, wb.x, wb.y, wb.z, wb.w};
#pragma unroll
    for (int u = 0; u < 8; ++u)
      a = fmaf(ww[u], __builtin_amdgcn_rcpf(exp2f(qv[u] + kk[u]) + 1.f), a);
  }
  scT[((size_t)b * LK_ + j) * LQ_ + i] = fmaf(-2.f, a, Wsum);  // coalesced
}

// =====================================================================
// Kernel C: masked softmax + AV, TI=4 rows/block, 512 thr, AV unroll x8.
// =====================================================================
__global__ __launch_bounds__(512) void softmax_av_kernel(
    const float* __restrict__ scT, const float* __restrict__ V,
    const int* __restrict__ valid_lens, float* __restrict__ out) {
  __shared__ float4 p4s[LK_];
  __shared__ float redm[8][4];
  __shared__ float reds[8][4];

  const int blk = blockIdx.x;
  const int b = blk >> 6;
  const int i0 = (blk & 63) * 4;
  const int vl = valid_lens[b];
  const int t = threadIdx.x;        // j
  const int lane = t & 63, wave = t >> 6;

  const bool valid = t < vl;
  float s[4], m[4];
  {
    float4 sv = {-3.0e38f, -3.0e38f, -3.0e38f, -3.0e38f};
    if (valid) sv = *(const float4*)&scT[((size_t)b * LK_ + t) * LQ_ + i0];
    s[0] = sv.x; s[1] = sv.y; s[2] = sv.z; s[3] = sv.w;
#pragma unroll
    for (int ii = 0; ii < 4; ++ii) m[ii] = s[ii];
  }
#pragma unroll
  for (int off = 32; off; off >>= 1)
#pragma unroll
    for (int ii = 0; ii < 4; ++ii) m[ii] = fmaxf(m[ii], __shfl_xor(m[ii], off));
  if (lane == 0)
#pragma unroll
    for (int ii = 0; ii < 4; ++ii) redm[wave][ii] = m[ii];
  __syncthreads();
  float e[4], sum[4];
#pragma unroll
  for (int ii = 0; ii < 4; ++ii) {
    float mx = redm[0][ii];
#pragma unroll
    for (int w = 1; w < 8; ++w) mx = fmaxf(mx, redm[w][ii]);
    e[ii] = valid ? __expf(s[ii] - mx) : 0.f;
    sum[ii] = e[ii];
  }
#pragma unroll
  for (int off = 32; off; off >>= 1)
#pragma unroll
    for (int ii = 0; ii < 4; ++ii) sum[ii] += __shfl_xor(sum[ii], off);
  if (lane == 0)
#pragma unroll
    for (int ii = 0; ii < 4; ++ii) reds[wave][ii] = sum[ii];
  __syncthreads();
  {
    float4 pv;
    float tot[4];
#pragma unroll
    for (int ii = 0; ii < 4; ++ii) {
      tot[ii] = reds[0][ii];
#pragma unroll
      for (int w = 1; w < 8; ++w) tot[ii] += reds[w][ii];
    }
    pv.x = e[0] * __builtin_amdgcn_rcpf(tot[0]);
    pv.y = e[1] * __builtin_amdgcn_rcpf(tot[1]);
    pv.z = e[2] * __builtin_amdgcn_rcpf(tot[2]);
    pv.w = e[3] * __builtin_amdgcn_rcpf(tot[3]);
    p4s[t] = pv;
  }
  __syncthreads();

  const float* __restrict__ Vb = V + (size_t)b * LK_ * DV_ + t;
  float a[4] = {0.f, 0.f, 0.f, 0.f};
  int j = 0;
  const int jv = vl & ~7;
  for (; j < jv; j += 8) {
    float v[8];
#pragma unroll
    for (int u = 0; u < 8; ++u) v[u] = Vb[(size_t)(j + u) * DV_];
#pragma unroll
    for (int u = 0; u < 8; ++u) {
      const float4 pp = p4s[j + u];
      a[0] = fmaf(pp.x, v[u], a[0]); a[1] = fmaf(pp.y, v[u], a[1]);
      a[2] = fmaf(pp.z, v[u], a[2]); a[3] = fmaf(pp.w, v[u], a[3]);
    }
  }
  for (; j < vl; ++j) {
    const float v = Vb[(size_t)j * DV_];
    const float4 pp = p4s[j];
    a[0] = fmaf(pp.x, v, a[0]); a[1] = fmaf(pp.y, v, a[1]);
    a[2] = fmaf(pp.z, v, a[2]); a[3] = fmaf(pp.w, v, a[3]);
  }
#pragma unroll
  for (int ii = 0; ii < 4; ++ii)
    out[(size_t)(b * LQ_ + i0 + ii) * DV_ + t] = a[ii];
}

extern "C" void kernel_launch(void* const* d_in, const int* in_sizes, int n_in,
                              void* d_out, int out_size, void* d_ws, size_t ws_size,
                              hipStream_t stream) {
  const float* queries    = (const float*)d_in[0];
  const float* keys       = (const float*)d_in[1];
  const float* values     = (const float*)d_in[2];
  const int*   valid_lens = (const int*)d_in[3];
  const float* Wq         = (const float*)d_in[4];
  const float* Wk         = (const float*)d_in[5];
  const float* wv         = (const float*)d_in[6];
  float* out = (float*)d_out;

  char* ws = (char*)d_ws;
  float* qT   = (float*)ws;                          // B*H*LQ  = 1 MB
  float* kp   = (float*)(ws + (size_t)(1 << 20));    // B*LK*H  = 2 MB
  float* scT  = (float*)(ws + (size_t)(3 << 20));    // B*LK*LQ = 2 MB
  float* wsum = (float*)(ws + (size_t)(5 << 20));    // 4 B

  proj_kernel<<<(B_ * LQ_ + B_ * LK_) / 8, 512, 0, stream>>>(
      queries, keys, Wq, Wk, wv, valid_lens, qT, kp, wsum);
  scores_kernel<<<(LK_ / 2) * B_, 512, 0, stream>>>(
      qT, kp, wv, wsum, valid_lens, scT);
  softmax_av_kernel<<<B_ * (LQ_ / 4), 512, 0, stream>>>(
      scT, values, valid_lens, out);
}

// Round 9
// 61.200 us; speedup vs baseline: 1.5584x; 1.1899x over previous
//
#include <hip/hip_runtime.h>

#define B_   4
#define LQ_  256
#define LK_  512
#define DIN_ 512
#define H_   256
#define DV_  512

#define L2E 1.4426950408889634f   // log2(e)

// tanh(x) = 1 - 2/(e^{2x}+1);  e^{2(q+k)} = (e^q * e^k)^2.
// proj stores eq = 2^clamp(qp*L2E,±126), ek likewise (never 0/inf -> no NaN;
// p*p over/underflow saturates tanh correctly).

// =====================================================================
// Kernel A: proj as LDS-shared GEMM, tile 16 rows x 64 h, TK=64, 256 thr.
// grid = 256 Q-blocks + 512 K-blocks (batch-interleaved; dead K tiles exit).
// thread micro-tile 2r x 2h. LDS 21.3 KB -> ~7 blocks/CU residency.
// Outputs: eqT[b][h][i] (transposed), ekp[b][j][h] (row-major).
// =====================================================================
__global__ __launch_bounds__(256) void proj_kernel(
    const float* __restrict__ Q, const float* __restrict__ K,
    const float* __restrict__ Wq, const float* __restrict__ Wk,
    const float* __restrict__ wv, const int* __restrict__ valid_lens,
    float* __restrict__ eqT, float* __restrict__ ekp, float* __restrict__ wsum) {
  __shared__ float xs[16][68];
  __shared__ float ws[64][68];

  const int blk = blockIdx.x;
  const bool isQ = blk < 256;
  int b, row0, h0;
  if (isQ) {                      // 64 row-tiles x 4 h-tiles
    const int rt = blk & 63;
    b = rt >> 4; row0 = (rt & 15) * 16; h0 = (blk >> 6) * 64;
  } else {                        // batch-interleaved: consecutive blocks differ in b
    const int u = blk - 256;      // [0,512)
    b = u & 3; row0 = ((u >> 2) & 31) * 16; h0 = (u >> 7) * 64;
    if (row0 >= valid_lens[b]) return;   // dead K tile (uniform, before barriers)
  }
  const float* __restrict__ X = (isQ ? Q : K) + ((size_t)(b * (isQ ? LQ_ : LK_) + row0)) * DIN_;
  const float* __restrict__ W = (isQ ? Wq : Wk) + h0;

  const int t  = threadIdx.x;
  const int hp = t & 31;          // h = 2hp, 2hp+1
  const int rp = t >> 5;          // rows 2rp, 2rp+1
  float a00 = 0.f, a01 = 0.f, a10 = 0.f, a11 = 0.f;

  const int sr = t >> 4, sc = (t & 15) * 4;   // staging coords
  for (int d0 = 0; d0 < DIN_; d0 += 64) {
    __syncthreads();
    *(float4*)&xs[sr][sc] = *(const float4*)&X[(size_t)sr * DIN_ + d0 + sc];
#pragma unroll
    for (int p = 0; p < 4; ++p)
      *(float4*)&ws[sr + 16 * p][sc] =
          *(const float4*)&W[(size_t)(d0 + sr + 16 * p) * H_ + sc];
    __syncthreads();

    for (int k = 0; k < 64; k += 8) {
      const float4 xa0 = *(const float4*)&xs[2 * rp][k];
      const float4 xb0 = *(const float4*)&xs[2 * rp][k + 4];
      const float4 xa1 = *(const float4*)&xs[2 * rp + 1][k];
      const float4 xb1 = *(const float4*)&xs[2 * rp + 1][k + 4];
      const float x0[8] = {xa0.x, xa0.y, xa0.z, xa0.w, xb0.x, xb0.y, xb0.z, xb0.w};
      const float x1[8] = {xa1.x, xa1.y, xa1.z, xa1.w, xb1.x, xb1.y, xb1.z, xb1.w};
#pragma unroll
      for (int u = 0; u < 8; ++u) {
        const float2 w2 = *(const float2*)&ws[k + u][2 * hp];
        a00 = fmaf(x0[u], w2.x, a00); a01 = fmaf(x0[u], w2.y, a01);
        a10 = fmaf(x1[u], w2.x, a10); a11 = fmaf(x1[u], w2.y, a11);
      }
    }
  }

  // exp-convert: eq/ek = 2^clamp(acc*log2e, +-126)  (finite, nonzero)
  const float e00 = exp2f(fminf(fmaxf(a00 * L2E, -126.f), 126.f));
  const float e01 = exp2f(fminf(fmaxf(a01 * L2E, -126.f), 126.f));
  const float e10 = exp2f(fminf(fmaxf(a10 * L2E, -126.f), 126.f));
  const float e11 = exp2f(fminf(fmaxf(a11 * L2E, -126.f), 126.f));

  if (isQ) {
    float2 o0 = {e00, e10};   // h=h0+2hp,   i = row0+2rp, +1
    float2 o1 = {e01, e11};   // h=h0+2hp+1
    *(float2*)&eqT[((size_t)b * H_ + h0 + 2 * hp) * LQ_ + row0 + 2 * rp] = o0;
    *(float2*)&eqT[((size_t)b * H_ + h0 + 2 * hp + 1) * LQ_ + row0 + 2 * rp] = o1;
  } else {
    float2 o0 = {e00, e01};   // row row0+2rp,   h pair
    float2 o1 = {e10, e11};   // row row0+2rp+1
    *(float2*)&ekp[(size_t)(b * LK_ + row0 + 2 * rp) * H_ + h0 + 2 * hp] = o0;
    *(float2*)&ekp[(size_t)(b * LK_ + row0 + 2 * rp + 1) * H_ + h0 + 2 * hp] = o1;
  }

  if (blk == 0 && t < 64) {
    float s = wv[t] + wv[t + 64] + wv[t + 128] + wv[t + 192];
#pragma unroll
    for (int off = 32; off; off >>= 1) s += __shfl_xor(s, off);
    if (t == 0) *wsum = s;
  }
}

// =====================================================================
// Kernel B: scoresT[b,j,i] = Wsum - 2*sum_h wv[h]*rcp((eq*ek)^2 + 1)
// 256 thr = 256 i; 2 j per thread (shared eq loads). Swizzled grid:
// u in [0,1024): s=u>>8, c=u&255, b=(c+s)&3, j0=2*(s*64+c>>2)  (bijective)
// -> each CU sees all batches at spread j-depths; dead blocks uniform.
// Inner: 1 trans + 3 VALU per element.
// =====================================================================
__global__ __launch_bounds__(256) void scores_kernel(
    const float* __restrict__ eqT, const float* __restrict__ ekp,
    const float* __restrict__ wv, const float* __restrict__ wsum,
    const int* __restrict__ valid_lens, float* __restrict__ scT) {
  const int u = blockIdx.x;
  const int s = u >> 8, c = u & 255;
  const int b = (c + s) & 3;
  const int j0 = 2 * (s * 64 + (c >> 2));
  const int vl = valid_lens[b];
  if (j0 >= vl) return;
  const int i = threadIdx.x;

  const float* __restrict__ eqcol = eqT + (size_t)b * H_ * LQ_ + i;
  const float* __restrict__ ek0 = ekp + (size_t)(b * LK_ + j0) * H_;  // uniform
  const float* __restrict__ ek1 = ek0 + H_;                           // uniform
  const float Wsum = *wsum;

  float a0 = 0.f, a1 = 0.f;
  for (int h = 0; h < H_; h += 8) {
    float qv[8];
#pragma unroll
    for (int uu = 0; uu < 8; ++uu) qv[uu] = eqcol[(size_t)(h + uu) * LQ_];  // coalesced
    const float4 k0a = *(const float4*)&ek0[h];
    const float4 k0b = *(const float4*)&ek0[h + 4];
    const float4 k1a = *(const float4*)&ek1[h];
    const float4 k1b = *(const float4*)&ek1[h + 4];
    const float4 wa  = *(const float4*)&wv[h];
    const float4 wb  = *(const float4*)&wv[h + 4];
    const float kk0[8] = {k0a.x, k0a.y, k0a.z, k0a.w, k0b.x, k0b.y, k0b.z, k0b.w};
    const float kk1[8] = {k1a.x, k1a.y, k1a.z, k1a.w, k1b.x, k1b.y, k1b.z, k1b.w};
    const float ww[8]  = {wa.x, wa.y, wa.z, wa.w, wb.x, wb.y, wb.z, wb.w};
#pragma unroll
    for (int uu = 0; uu < 8; ++uu) {
      const float p0 = qv[uu] * kk0[uu];
      const float p1 = qv[uu] * kk1[uu];
      a0 = fmaf(ww[uu], __builtin_amdgcn_rcpf(fmaf(p0, p0, 1.f)), a0);
      a1 = fmaf(ww[uu], __builtin_amdgcn_rcpf(fmaf(p1, p1, 1.f)), a1);
    }
  }
  scT[(size_t)(b * LK_ + j0) * LQ_ + i] = fmaf(-2.f, a0, Wsum);
  if (j0 + 1 < vl)
    scT[(size_t)(b * LK_ + j0 + 1) * LQ_ + i] = fmaf(-2.f, a1, Wsum);
}

// =====================================================================
// Kernel C: masked softmax + AV, TI=4 rows/block, 512 thr, AV unroll x8.
// =====================================================================
__global__ __launch_bounds__(512) void softmax_av_kernel(
    const float* __restrict__ scT, const float* __restrict__ V,
    const int* __restrict__ valid_lens, float* __restrict__ out) {
  __shared__ float4 p4s[LK_];
  __shared__ float redm[8][4];
  __shared__ float reds[8][4];

  const int blk = blockIdx.x;
  const int b = blk >> 6;
  const int i0 = (blk & 63) * 4;
  const int vl = valid_lens[b];
  const int t = threadIdx.x;        // j
  const int lane = t & 63, wave = t >> 6;

  const bool valid = t < vl;
  float s[4], m[4];
  {
    float4 sv = {-3.0e38f, -3.0e38f, -3.0e38f, -3.0e38f};
    if (valid) sv = *(const float4*)&scT[((size_t)b * LK_ + t) * LQ_ + i0];
    s[0] = sv.x; s[1] = sv.y; s[2] = sv.z; s[3] = sv.w;
#pragma unroll
    for (int ii = 0; ii < 4; ++ii) m[ii] = s[ii];
  }
#pragma unroll
  for (int off = 32; off; off >>= 1)
#pragma unroll
    for (int ii = 0; ii < 4; ++ii) m[ii] = fmaxf(m[ii], __shfl_xor(m[ii], off));
  if (lane == 0)
#pragma unroll
    for (int ii = 0; ii < 4; ++ii) redm[wave][ii] = m[ii];
  __syncthreads();
  float e[4], sum[4];
#pragma unroll
  for (int ii = 0; ii < 4; ++ii) {
    float mx = redm[0][ii];
#pragma unroll
    for (int w = 1; w < 8; ++w) mx = fmaxf(mx, redm[w][ii]);
    e[ii] = valid ? __expf(s[ii] - mx) : 0.f;
    sum[ii] = e[ii];
  }
#pragma unroll
  for (int off = 32; off; off >>= 1)
#pragma unroll
    for (int ii = 0; ii < 4; ++ii) sum[ii] += __shfl_xor(sum[ii], off);
  if (lane == 0)
#pragma unroll
    for (int ii = 0; ii < 4; ++ii) reds[wave][ii] = sum[ii];
  __syncthreads();
  {
    float4 pv;
    float tot[4];
#pragma unroll
    for (int ii = 0; ii < 4; ++ii) {
      tot[ii] = reds[0][ii];
#pragma unroll
      for (int w = 1; w < 8; ++w) tot[ii] += reds[w][ii];
    }
    pv.x = e[0] * __builtin_amdgcn_rcpf(tot[0]);
    pv.y = e[1] * __builtin_amdgcn_rcpf(tot[1]);
    pv.z = e[2] * __builtin_amdgcn_rcpf(tot[2]);
    pv.w = e[3] * __builtin_amdgcn_rcpf(tot[3]);
    p4s[t] = pv;
  }
  __syncthreads();

  const float* __restrict__ Vb = V + (size_t)b * LK_ * DV_ + t;
  float a[4] = {0.f, 0.f, 0.f, 0.f};
  int j = 0;
  const int jv = vl & ~7;
  for (; j < jv; j += 8) {
    float v[8];
#pragma unroll
    for (int u = 0; u < 8; ++u) v[u] = Vb[(size_t)(j + u) * DV_];
#pragma unroll
    for (int u = 0; u < 8; ++u) {
      const float4 pp = p4s[j + u];
      a[0] = fmaf(pp.x, v[u], a[0]); a[1] = fmaf(pp.y, v[u], a[1]);
      a[2] = fmaf(pp.z, v[u], a[2]); a[3] = fmaf(pp.w, v[u], a[3]);
    }
  }
  for (; j < vl; ++j) {
    const float v = Vb[(size_t)j * DV_];
    const float4 pp = p4s[j];
    a[0] = fmaf(pp.x, v, a[0]); a[1] = fmaf(pp.y, v, a[1]);
    a[2] = fmaf(pp.z, v, a[2]); a[3] = fmaf(pp.w, v, a[3]);
  }
#pragma unroll
  for (int ii = 0; ii < 4; ++ii)
    out[(size_t)(b * LQ_ + i0 + ii) * DV_ + t] = a[ii];
}

extern "C" void kernel_launch(void* const* d_in, const int* in_sizes, int n_in,
                              void* d_out, int out_size, void* d_ws, size_t ws_size,
                              hipStream_t stream) {
  const float* queries    = (const float*)d_in[0];
  const float* keys       = (const float*)d_in[1];
  const float* values     = (const float*)d_in[2];
  const int*   valid_lens = (const int*)d_in[3];
  const float* Wq         = (const float*)d_in[4];
  const float* Wk         = (const float*)d_in[5];
  const float* wv         = (const float*)d_in[6];
  float* out = (float*)d_out;

  char* ws = (char*)d_ws;
  float* eqT  = (float*)ws;                          // B*H*LQ  = 1 MB
  float* ekp  = (float*)(ws + (size_t)(1 << 20));    // B*LK*H  = 2 MB
  float* scT  = (float*)(ws + (size_t)(3 << 20));    // B*LK*LQ = 2 MB
  float* wsum = (float*)(ws + (size_t)(5 << 20));    // 4 B

  proj_kernel<<<768, 256, 0, stream>>>(
      queries, keys, Wq, Wk, wv, valid_lens, eqT, ekp, wsum);
  scores_kernel<<<1024, 256, 0, stream>>>(
      eqT, ekp, wv, wsum, valid_lens, scT);
  softmax_av_kernel<<<B_ * (LQ_ / 4), 512, 0, stream>>>(
      scT, values, valid_lens, out);
}